// Round 1
// baseline (389.630 us; speedup 1.0000x reference)
//
#include <hip/hip_runtime.h>
#include <math.h>

#define BB 32
#define SS 512
#define HH 256
#define TT 48
#define START_IDX 46
#define STOP_IDX 47

// ---------------------------------------------------------------------------
// Kernel 1: emission GEMM  em[r][t] = dot(f[r,:], w[:,t]) + bias[t]
//   r = b*S+s in [0,16384), t in [0,48), K = 256.
//   Block: 256 threads = 4 waves; block handles 64 rows; wave cg handles 12 cols.
// ---------------------------------------------------------------------------
__global__ __launch_bounds__(256) void emission_kernel(
    const float* __restrict__ f,     // [B*S, H]
    const float* __restrict__ w,     // [H, T]
    const float* __restrict__ bias,  // [T]
    float* __restrict__ em)          // [B*S, T]
{
    __shared__ __align__(16) float wlds[HH * TT];   // 48 KiB
    const int tid = threadIdx.x;
    for (int idx = tid; idx < HH * TT; idx += 256) wlds[idx] = w[idx];
    __syncthreads();

    const int row = blockIdx.x * 64 + (tid & 63);
    const int cg  = tid >> 6;       // 0..3 (uniform per wave)
    const int c0  = cg * 12;

    float acc[12];
#pragma unroll
    for (int c = 0; c < 12; ++c) acc[c] = bias[c0 + c];

    const float4* f4 = (const float4*)(f + (size_t)row * HH);
#pragma unroll 4
    for (int k4 = 0; k4 < HH / 4; ++k4) {
        float4 fv = f4[k4];
        const int kb = k4 * 4;
        const float* wr0 = &wlds[(kb + 0) * TT + c0];
        const float* wr1 = &wlds[(kb + 1) * TT + c0];
        const float* wr2 = &wlds[(kb + 2) * TT + c0];
        const float* wr3 = &wlds[(kb + 3) * TT + c0];
#pragma unroll
        for (int c = 0; c < 12; ++c) {
            acc[c] += fv.x * wr0[c];
            acc[c] += fv.y * wr1[c];
            acc[c] += fv.z * wr2[c];
            acc[c] += fv.w * wr3[c];
        }
    }
    float4* emv = (float4*)(em + (size_t)row * TT + c0);
#pragma unroll
    for (int q = 0; q < 3; ++q)
        emv[q] = make_float4(acc[4*q+0], acc[4*q+1], acc[4*q+2], acc[4*q+3]);
}

// ---------------------------------------------------------------------------
// Kernel 2: forward algorithm + gold score + output. One wave per batch elem.
//   Lane j owns alpha_j and E[:,j]=exp(trans[:,j]) in registers.
//   new_alpha[j] = em[t,j] + m + log( sum_i exp(alpha_i - m) * E[i][j] )
// ---------------------------------------------------------------------------
__global__ __launch_bounds__(64) void crf_scan_kernel(
    const float* __restrict__ em,      // [B*S, T]
    const float* __restrict__ trans,   // [T, T]
    const int*   __restrict__ lengths, // [B]
    const int*   __restrict__ tags,    // [B, S]
    float* __restrict__ out)           // [B]
{
    __shared__ __align__(16) float tlds[TT * TT];   // raw transitions, 9 KiB
    __shared__ __align__(16) float plds[64];

    const int j = threadIdx.x;   // 0..63; tags j>=48 are padding lanes
    const int b = blockIdx.x;

    for (int idx = j; idx < TT * TT; idx += 64) tlds[idx] = trans[idx];
    __syncthreads();

    const int len = lengths[b];  // in [256, 512]

    // ---- gold path score (parallel over s across all 64 lanes) ----
    float g = 0.0f;
    for (int s = j; s < len; s += 64) {
        const int tag  = tags[b * SS + s];
        const int from = (s == 0) ? START_IDX : tags[b * SS + s - 1];
        g += em[(size_t)(b * SS + s) * TT + tag] + tlds[from * TT + tag];
    }
    g += __shfl_xor(g, 32);
    g += __shfl_xor(g, 16);
    g += __shfl_xor(g, 8);
    g += __shfl_xor(g, 4);
    g += __shfl_xor(g, 2);
    g += __shfl_xor(g, 1);
    // g: total gold emission+transition sum, same in every lane

    // ---- E column in registers ----
    const int jj = (j < TT) ? j : (TT - 1);   // clamped col for padding lanes
    float E[TT];
#pragma unroll
    for (int i = 0; i < TT; ++i) {
        const float tv = tlds[i * TT + jj];
        E[i] = (j < TT) ? __expf(tv) : 0.0f;  // exp(-10000) underflows to 0
    }

    // ---- forward scan ----
    const float* emb = em + (size_t)b * SS * TT;
    float alpha = (j == START_IDX) ? 0.0f : -INFINITY;

    float em_c  = emb[0 * TT + jj];
    float em_n1 = emb[1 * TT + jj];

    for (int t = 0; t < len; ++t) {
        // prefetch emission row t+2 (clamped) to cover global latency
        int tp = t + 2; if (tp > SS - 1) tp = SS - 1;
        const float em_n2 = emb[(size_t)tp * TT + jj];

        // wave max of alpha (padding lanes hold -inf)
        float m = alpha;
        m = fmaxf(m, __shfl_xor(m, 32));
        m = fmaxf(m, __shfl_xor(m, 16));
        m = fmaxf(m, __shfl_xor(m, 8));
        m = fmaxf(m, __shfl_xor(m, 4));
        m = fmaxf(m, __shfl_xor(m, 2));
        m = fmaxf(m, __shfl_xor(m, 1));

        const float p = __expf(alpha - m);   // in [0,1]; 0 for -inf lanes
        plds[j] = p;
        __syncthreads();

        float ax = 0.f, ay = 0.f, az = 0.f, aw = 0.f;
        const float4* p4 = (const float4*)plds;
#pragma unroll
        for (int i4 = 0; i4 < TT / 4; ++i4) {
            const float4 pv = p4[i4];     // broadcast LDS read
            ax += pv.x * E[4*i4+0];
            ay += pv.y * E[4*i4+1];
            az += pv.z * E[4*i4+2];
            aw += pv.w * E[4*i4+3];
        }
        const float dot = (ax + ay) + (az + aw);   // 0 for START col -> -inf

        alpha = em_c + m + __logf(dot);
        em_c = em_n1; em_n1 = em_n2;
        __syncthreads();   // protect plds WAR for next iteration
    }

    // ---- terminal logsumexp: alpha + trans[:, STOP] ----
    float term = (j < TT) ? (alpha + tlds[j * TT + STOP_IDX]) : -INFINITY;
    float mT = term;
    mT = fmaxf(mT, __shfl_xor(mT, 32));
    mT = fmaxf(mT, __shfl_xor(mT, 16));
    mT = fmaxf(mT, __shfl_xor(mT, 8));
    mT = fmaxf(mT, __shfl_xor(mT, 4));
    mT = fmaxf(mT, __shfl_xor(mT, 2));
    mT = fmaxf(mT, __shfl_xor(mT, 1));
    float e = __expf(term - mT);   // 0 for -inf lanes
    e += __shfl_xor(e, 32);
    e += __shfl_xor(e, 16);
    e += __shfl_xor(e, 8);
    e += __shfl_xor(e, 4);
    e += __shfl_xor(e, 2);
    e += __shfl_xor(e, 1);
    const float all_paths = mT + __logf(e);

    if (j == 0) {
        const int last = tags[b * SS + len - 1];
        const float gold = g + tlds[last * TT + STOP_IDX];
        out[b] = all_paths - gold;
    }
}

// ---------------------------------------------------------------------------
extern "C" void kernel_launch(void* const* d_in, const int* in_sizes, int n_in,
                              void* d_out, int out_size, void* d_ws, size_t ws_size,
                              hipStream_t stream) {
    const float* f       = (const float*)d_in[0];  // lstm_features [B,S,H]
    const float* w       = (const float*)d_in[1];  // emission_w   [H,T]
    const float* bias    = (const float*)d_in[2];  // emission_b   [T]
    const float* trans   = (const float*)d_in[3];  // transitions  [T,T]
    const int*   lengths = (const int*)d_in[4];    // [B]
    const int*   tags    = (const int*)d_in[5];    // [B,S]
    float*       out     = (float*)d_out;          // [B]

    float* em = (float*)d_ws;                      // [B*S, T] = 3.1 MB scratch

    emission_kernel<<<(BB * SS) / 64, 256, 0, stream>>>(f, w, bias, em);
    crf_scan_kernel<<<BB, 64, 0, stream>>>(em, trans, lengths, tags, out);
}

// Round 2
// 256.672 us; speedup vs baseline: 1.5180x; 1.5180x over previous
//
#include <hip/hip_runtime.h>
#include <math.h>

#define BB 32
#define SS 512
#define HH 256
#define TT 48
#define START_IDX 46
#define STOP_IDX 47

__device__ __forceinline__ float rfl(float x) {
    return __int_as_float(__builtin_amdgcn_readfirstlane(__float_as_int(x)));
}

// ---------------------------------------------------------------------------
// Kernel 1: emission GEMM  em[r][t] = dot(f[r,:], w[:,t]) + bias[t]
//   256 blocks x 256 thr; block = 64 rows, wave cg = 12 cols.
//   w/bias accessed via wave-uniform scalar loads (SGPR broadcast) -> VALU-bound.
// ---------------------------------------------------------------------------
__global__ __launch_bounds__(256) void emission_kernel(
    const float* __restrict__ f,     // [B*S, H]
    const float* __restrict__ w,     // [H, T]
    const float* __restrict__ bias,  // [T]
    float* __restrict__ em)          // [B*S, T]
{
    const int tid = threadIdx.x;
    const int row = blockIdx.x * 64 + (tid & 63);
    const int c0u = __builtin_amdgcn_readfirstlane((tid >> 6) * 12);  // wave-uniform

    float acc[12];
#pragma unroll
    for (int c = 0; c < 12; ++c) acc[c] = bias[c0u + c];   // scalar loads

    const float4* f4 = (const float4*)(f + (size_t)row * HH);
    const float* wbase = w + c0u;
#pragma unroll 4
    for (int k4 = 0; k4 < HH / 4; ++k4) {
        const float4 fv = f4[k4];
        const float* wr = wbase + k4 * 4 * TT;   // wave-uniform -> s_load
#pragma unroll
        for (int c = 0; c < 12; ++c) {
            float a = acc[c];
            a = fmaf(fv.x, wr[c], a);
            a = fmaf(fv.y, wr[TT + c], a);
            a = fmaf(fv.z, wr[2 * TT + c], a);
            a = fmaf(fv.w, wr[3 * TT + c], a);
            acc[c] = a;
        }
    }
    float4* emv = (float4*)(em + (size_t)row * TT + c0u);
#pragma unroll
    for (int q = 0; q < 3; ++q)
        emv[q] = make_float4(acc[4*q+0], acc[4*q+1], acc[4*q+2], acc[4*q+3]);
}

// ---------------------------------------------------------------------------
// Kernel 2: forward scan in scaled linear space. One wave per batch element.
//   q_j = exp(alpha_j)/Z.  Per step:
//     s_j = sum_i q_i * E[i][j]          (LDS broadcast + 48 FMA)
//     q'_j = s_j * (exp(em[t][j]) / d)   (d = lane0's s from PREVIOUS step)
//     logZ += log(d)
//   No barriers: single wave, DS ops execute in issue order.
//   exp / log / rcp / readfirstlane are all off the loop-carried chain.
// ---------------------------------------------------------------------------
__global__ __launch_bounds__(64) void crf_scan_kernel(
    const float* __restrict__ em,      // [B*S, T]
    const float* __restrict__ trans,   // [T, T]
    const int*   __restrict__ lengths, // [B]
    const int*   __restrict__ tags,    // [B, S]
    float* __restrict__ out)           // [B]
{
    __shared__ __align__(16) float tlds[TT * TT];
    __shared__ __align__(16) float qlds[64];

    const int j = threadIdx.x;   // 0..63; lanes j>=48 are padding
    const int b = blockIdx.x;

    for (int idx = j; idx < TT * TT; idx += 64) tlds[idx] = trans[idx];
    __builtin_amdgcn_wave_barrier();

    const int len = lengths[b];  // in [256, 512]

    // ---- gold path score (parallel over s across lanes) ----
    float g = 0.0f;
    for (int s = j; s < len; s += 64) {
        const int tag  = tags[b * SS + s];
        const int from = (s == 0) ? START_IDX : tags[b * SS + s - 1];
        g += em[(size_t)(b * SS + s) * TT + tag] + tlds[from * TT + tag];
    }
    g += __shfl_xor(g, 32);
    g += __shfl_xor(g, 16);
    g += __shfl_xor(g, 8);
    g += __shfl_xor(g, 4);
    g += __shfl_xor(g, 2);
    g += __shfl_xor(g, 1);

    // ---- E columns in registers ----
    const int jj = (j < TT) ? j : (TT - 1);
    float E[TT];
#pragma unroll
    for (int i = 0; i < TT; ++i)
        E[i] = (j < TT) ? __expf(tlds[i * TT + jj]) : 0.0f;  // exp(-1e4) -> 0
    const float Estop = (j < TT) ? __expf(tlds[j * TT + STOP_IDX]) : 0.0f;

    // ---- init scan state ----
    qlds[j] = (j == START_IDX) ? 1.0f : 0.0f;
    __builtin_amdgcn_wave_barrier();

    const float* emb = em + (size_t)b * SS * TT;
    float e1 = emb[1 * TT + jj];
    float e2 = emb[2 * TT + jj];
    float e3 = emb[3 * TT + jj];
    float fac   = __expf(emb[0 * TT + jj]);  // exp(em[0])/1
    float dprev = 1.0f;
    float L     = 0.0f;
    float qn    = 0.0f;

    for (int t = 0; t < len; ++t) {
        int tp = t + 4; tp = (tp < SS) ? tp : (SS - 1);
        const float enext = emb[(size_t)tp * TT + jj];   // global prefetch

        // ---- dot: s_j = sum_i qlds[i] * E[i][j]  (broadcast reads) ----
        const float4* p4 = (const float4*)qlds;
        float part[12];
#pragma unroll
        for (int i4 = 0; i4 < 12; ++i4) {
            const float4 pv = p4[i4];
            float u = pv.x * E[4*i4+0];
            u = fmaf(pv.y, E[4*i4+1], u);
            u = fmaf(pv.z, E[4*i4+2], u);
            u = fmaf(pv.w, E[4*i4+3], u);
            part[i4] = u;
        }
        const float s = (((part[0] + part[1]) + (part[2] + part[3]))
                       + ((part[4] + part[5]) + (part[6] + part[7])))
                       + ((part[8] + part[9]) + (part[10] + part[11]));

        qn = s * fac;                 // normalizer d folded into fac
        __builtin_amdgcn_wave_barrier();
        qlds[j] = qn;                 // padding lanes write 0 (E col = 0)
        __builtin_amdgcn_wave_barrier();

        // ---- off-chain bookkeeping for next step ----
        L += __logf(dprev);           // log of normalizer APPLIED this step
        const float dd = rfl(s);      // lane 0 (tag 0): strictly positive
        dprev = dd;
        fac = __expf(e1) * (1.0f / dd);
        e1 = e2; e2 = e3; e3 = enext;
    }

    // ---- terminal: all_paths = L + log( sum_j q_j * exp(trans[j][STOP]) ) ----
    float v = qn * Estop;
    v += __shfl_xor(v, 32);
    v += __shfl_xor(v, 16);
    v += __shfl_xor(v, 8);
    v += __shfl_xor(v, 4);
    v += __shfl_xor(v, 2);
    v += __shfl_xor(v, 1);
    const float all_paths = L + __logf(v);

    if (j == 0) {
        const int last = tags[b * SS + len - 1];
        out[b] = all_paths - (g + tlds[last * TT + STOP_IDX]);
    }
}

// ---------------------------------------------------------------------------
extern "C" void kernel_launch(void* const* d_in, const int* in_sizes, int n_in,
                              void* d_out, int out_size, void* d_ws, size_t ws_size,
                              hipStream_t stream) {
    const float* f       = (const float*)d_in[0];
    const float* w       = (const float*)d_in[1];
    const float* bias    = (const float*)d_in[2];
    const float* trans   = (const float*)d_in[3];
    const int*   lengths = (const int*)d_in[4];
    const int*   tags    = (const int*)d_in[5];
    float*       out     = (float*)d_out;

    float* em = (float*)d_ws;   // [B*S, T] scratch, 3.1 MB

    emission_kernel<<<(BB * SS) / 64, 256, 0, stream>>>(f, w, bias, em);
    crf_scan_kernel<<<BB, 64, 0, stream>>>(em, trans, lengths, tags, out);
}

// Round 3
// 225.518 us; speedup vs baseline: 1.7277x; 1.1381x over previous
//
#include <hip/hip_runtime.h>
#include <math.h>

#define BB 32
#define SS 512
#define HH 256
#define TT 48
#define START_IDX 46
#define STOP_IDX 47

__device__ __forceinline__ float rfl(float x) {
    return __int_as_float(__builtin_amdgcn_readfirstlane(__float_as_int(x)));
}

// ---------------------------------------------------------------------------
// Kernel 1: exem[r][t] = exp( dot(f[r,:], w[:,t]) + bias[t] )
//   256 blocks x 256 thr. Stage contiguous 64KB f-tile into LDS (coalesced),
//   compute 12 cols/thread from padded LDS rows; W via wave-uniform s_loads.
// ---------------------------------------------------------------------------
__global__ __launch_bounds__(256) void emission_kernel(
    const float* __restrict__ f,     // [B*S, H]
    const float* __restrict__ w,     // [H, T]
    const float* __restrict__ bias,  // [T]
    float* __restrict__ exem)        // [B*S, T]
{
    __shared__ __align__(16) float flds[64 * 260];   // 64 rows, stride 260
    const int tid  = threadIdx.x;
    const int row0 = blockIdx.x * 64;

    // coalesced stage: 64 rows x 256 floats = 4096 float4, contiguous in HBM
    const float4* src = (const float4*)(f + (size_t)row0 * HH);
#pragma unroll
    for (int it = 0; it < 16; ++it) {
        const int i  = tid + it * 256;
        const float4 v = src[i];
        const int r  = i >> 6;     // / 64 float4s per row
        const int k4 = i & 63;
        *(float4*)&flds[r * 260 + k4 * 4] = v;   // 260*4B row stride, 16B aligned
    }
    __syncthreads();

    const int lane = tid & 63;
    const int c0u  = __builtin_amdgcn_readfirstlane((tid >> 6) * 12);

    float acc[12];
#pragma unroll
    for (int c = 0; c < 12; ++c) acc[c] = bias[c0u + c];   // scalar loads

    const float* wbase = w + c0u;
    const float* frow  = &flds[lane * 260];
#pragma unroll 8
    for (int k4 = 0; k4 < 64; ++k4) {
        const float4 fv = *(const float4*)&frow[k4 * 4];
        const float* wr = wbase + (size_t)k4 * 4 * TT;   // wave-uniform -> s_load
#pragma unroll
        for (int c = 0; c < 12; ++c) {
            float a = acc[c];
            a = fmaf(fv.x, wr[c], a);
            a = fmaf(fv.y, wr[TT + c], a);
            a = fmaf(fv.z, wr[2 * TT + c], a);
            a = fmaf(fv.w, wr[3 * TT + c], a);
            acc[c] = a;
        }
    }
    float4* ev = (float4*)(exem + (size_t)(row0 + lane) * TT + c0u);
#pragma unroll
    for (int q = 0; q < 3; ++q)
        ev[q] = make_float4(__expf(acc[4*q+0]), __expf(acc[4*q+1]),
                            __expf(acc[4*q+2]), __expf(acc[4*q+3]));
}

// ---------------------------------------------------------------------------
// Kernel 2: forward scan, scaled linear space, one wave per batch.
//   Pair-unrolled: step A no normalizer; step B applies 1/dd (dd = lane0 of sA)
//   computed OFF the LDS round-trip chain. No barriers (single-wave in-order DS).
// ---------------------------------------------------------------------------
__global__ __launch_bounds__(64) void crf_scan_kernel(
    const float* __restrict__ exem,    // [B*S, T] = exp(emission)
    const float* __restrict__ trans,   // [T, T]
    const int*   __restrict__ lengths, // [B]
    const int*   __restrict__ tags,    // [B, S]
    float* __restrict__ out)           // [B]
{
    __shared__ __align__(16) float tlds[TT * TT];
    __shared__ __align__(16) float q[64];

    const int j = threadIdx.x;
    const int b = blockIdx.x;

    for (int idx = j; idx < TT * TT; idx += 64) tlds[idx] = trans[idx];
    __builtin_amdgcn_wave_barrier();

    const int len = lengths[b];

    // ---- gold path score ----
    float g = 0.0f;
    for (int s = j; s < len; s += 64) {
        const int tag  = tags[b * SS + s];
        const int from = (s == 0) ? START_IDX : tags[b * SS + s - 1];
        g += __logf(exem[(size_t)(b * SS + s) * TT + tag]) + tlds[from * TT + tag];
    }
    g += __shfl_xor(g, 32); g += __shfl_xor(g, 16); g += __shfl_xor(g, 8);
    g += __shfl_xor(g, 4);  g += __shfl_xor(g, 2);  g += __shfl_xor(g, 1);

    // ---- E columns in registers ----
    const int jj = (j < TT) ? j : (TT - 1);
    float E[TT];
#pragma unroll
    for (int i = 0; i < TT; ++i)
        E[i] = (j < TT) ? __expf(tlds[i * TT + jj]) : 0.0f;
    const float Estop = (j < TT) ? __expf(tlds[j * TT + STOP_IDX]) : 0.0f;

    q[j] = (j == START_IDX) ? 1.0f : 0.0f;
    __builtin_amdgcn_wave_barrier();

    const float* emb = exem + (size_t)b * SS * TT;
    // emission register pipeline, distance 2 pairs
    float e0 = emb[0 * TT + jj];
    float e1 = emb[1 * TT + jj];
    float e2 = emb[2 * TT + jj];
    float e3 = emb[3 * TT + jj];

    float L = 0.0f, qn = 0.0f;
    const int npair = len >> 1;

    for (int p = 0; p < npair; ++p) {
        const int t = p * 2;
        int ta = t + 4; ta = (ta < SS) ? ta : (SS - 1);
        int tb = t + 5; tb = (tb < SS) ? tb : (SS - 1);
        const float fA = emb[(size_t)ta * TT + jj];
        const float fB = emb[(size_t)tb * TT + jj];

        // ---- step A: sA = q . E-col,  qA = sA * exem_t ----
        const float4* p4 = (const float4*)q;
        float pa[12];
#pragma unroll
        for (int i4 = 0; i4 < 12; ++i4) {
            const float4 pv = p4[i4];
            float u = pv.x * E[4*i4+0];
            u = fmaf(pv.y, E[4*i4+1], u);
            u = fmaf(pv.z, E[4*i4+2], u);
            u = fmaf(pv.w, E[4*i4+3], u);
            pa[i4] = u;
        }
        const float sA = (((pa[0]+pa[1]) + (pa[2]+pa[3]))
                        + ((pa[4]+pa[5]) + (pa[6]+pa[7])))
                        + ((pa[8]+pa[9]) + (pa[10]+pa[11]));
        q[j] = sA * e0;

        // off-chain: normalizer for step B (overlaps step B's LDS round trip)
        const float dd   = rfl(sA);
        const float facB = e1 * __builtin_amdgcn_rcpf(dd);

        // ---- step B: sB = qA . E-col,  qB = sB * exem_{t+1} / dd ----
        float pb[12];
#pragma unroll
        for (int i4 = 0; i4 < 12; ++i4) {
            const float4 pv = p4[i4];
            float u = pv.x * E[4*i4+0];
            u = fmaf(pv.y, E[4*i4+1], u);
            u = fmaf(pv.z, E[4*i4+2], u);
            u = fmaf(pv.w, E[4*i4+3], u);
            pb[i4] = u;
        }
        const float sB = (((pb[0]+pb[1]) + (pb[2]+pb[3]))
                        + ((pb[4]+pb[5]) + (pb[6]+pb[7])))
                        + ((pb[8]+pb[9]) + (pb[10]+pb[11]));
        qn = sB * facB;
        q[j] = qn;

        L += __logf(dd);
        e0 = e2; e1 = e3; e2 = fA; e3 = fB;
    }

    if (len & 1) {   // tail step, no normalizer (terminal log absorbs scale)
        const float4* p4 = (const float4*)q;
        float pt[12];
#pragma unroll
        for (int i4 = 0; i4 < 12; ++i4) {
            const float4 pv = p4[i4];
            float u = pv.x * E[4*i4+0];
            u = fmaf(pv.y, E[4*i4+1], u);
            u = fmaf(pv.z, E[4*i4+2], u);
            u = fmaf(pv.w, E[4*i4+3], u);
            pt[i4] = u;
        }
        const float sT = (((pt[0]+pt[1]) + (pt[2]+pt[3]))
                        + ((pt[4]+pt[5]) + (pt[6]+pt[7])))
                        + ((pt[8]+pt[9]) + (pt[10]+pt[11]));
        qn = sT * e0;
        q[j] = qn;
    }

    // ---- terminal: all_paths = L + log( sum_j q_j * exp(trans[j][STOP]) ) ----
    float v = qn * Estop;
    v += __shfl_xor(v, 32); v += __shfl_xor(v, 16); v += __shfl_xor(v, 8);
    v += __shfl_xor(v, 4);  v += __shfl_xor(v, 2);  v += __shfl_xor(v, 1);
    const float all_paths = L + __logf(v);

    if (j == 0) {
        const int last = tags[b * SS + len - 1];
        out[b] = all_paths - (g + tlds[last * TT + STOP_IDX]);
    }
}

// ---------------------------------------------------------------------------
extern "C" void kernel_launch(void* const* d_in, const int* in_sizes, int n_in,
                              void* d_out, int out_size, void* d_ws, size_t ws_size,
                              hipStream_t stream) {
    const float* f       = (const float*)d_in[0];
    const float* w       = (const float*)d_in[1];
    const float* bias    = (const float*)d_in[2];
    const float* trans   = (const float*)d_in[3];
    const int*   lengths = (const int*)d_in[4];
    const int*   tags    = (const int*)d_in[5];
    float*       out     = (float*)d_out;

    float* exem = (float*)d_ws;   // [B*S, T] scratch, 3.1 MB

    emission_kernel<<<(BB * SS) / 64, 256, 0, stream>>>(f, w, bias, exem);
    crf_scan_kernel<<<BB, 64, 0, stream>>>(exem, trans, lengths, tags, out);
}

// Round 4
// 188.926 us; speedup vs baseline: 2.0623x; 1.1937x over previous
//
#include <hip/hip_runtime.h>
#include <math.h>

#define BB 32
#define SS 512
#define HH 256
#define TT 48
#define START_IDX 46
#define STOP_IDX 47

typedef __attribute__((ext_vector_type(8))) short short8;
typedef __attribute__((ext_vector_type(4))) float floatx4;

__device__ __forceinline__ float rfl(float x) {
    return __int_as_float(__builtin_amdgcn_readfirstlane(__float_as_int(x)));
}
__device__ __forceinline__ unsigned short bf16_rne(float x) {
    const unsigned int u = __float_as_uint(x);
    return (unsigned short)((u + 0x7fffu + ((u >> 16) & 1u)) >> 16);
}
__device__ __forceinline__ float bf16_to_f32(unsigned short h) {
    return __uint_as_float(((unsigned int)h) << 16);
}

// ---------------------------------------------------------------------------
// Kernel 1: exem[r][t] = exp( dot(f[r,:], w[:,t]) + bias[t] )  via bf16 MFMA.
//   256 blocks x 256 thr (4 waves). Whole w lives in 24 B-frags = 96 VGPR/wave.
//   Wave handles one 16-row M-tile; K = 256 = 8 k-tiles of 32.
// ---------------------------------------------------------------------------
__global__ __launch_bounds__(256) void emission_kernel(
    const float* __restrict__ f,     // [B*S, H]
    const float* __restrict__ w,     // [H, T]
    const float* __restrict__ bias,  // [T]
    float* __restrict__ exem)        // [B*S, T]
{
    __shared__ __align__(16) unsigned short wb[HH * 50];  // bf16 w, padded rows
    __shared__ __align__(16) uint4 fragbuf[24 * 64];      // 24 B-frags x 64 lanes
    __shared__ float biaslds[TT];

    const int tid = threadIdx.x;

    // stage w -> bf16 LDS (coalesced global reads)
    for (int idx = tid; idx < HH * TT; idx += 256) {
        const int r = idx / TT;
        const int c = idx - r * TT;
        wb[r * 50 + c] = bf16_rne(w[idx]);
    }
    if (tid < TT) biaslds[tid] = bias[tid];
    __syncthreads();

    // build B-frags cooperatively: frag fb=(kt*3+nt); lane l: B[kt*32+q*8+i][nt*16+n]
    for (int idx = tid; idx < 24 * 64; idx += 256) {
        const int fb = idx >> 6;
        const int l  = idx & 63;
        const int kt = fb / 3;
        const int nt = fb - kt * 3;
        const int kbase = kt * 32 + (l >> 4) * 8;
        const int col   = nt * 16 + (l & 15);
        unsigned int p[4];
#pragma unroll
        for (int h = 0; h < 4; ++h) {
            const unsigned int lo = wb[(kbase + 2 * h)     * 50 + col];
            const unsigned int hi = wb[(kbase + 2 * h + 1) * 50 + col];
            p[h] = lo | (hi << 16);
        }
        fragbuf[idx] = make_uint4(p[0], p[1], p[2], p[3]);
    }
    __syncthreads();

    const int lane = tid & 63;
    const int wv   = tid >> 6;

    short8 Bf[24];
#pragma unroll
    for (int fb = 0; fb < 24; ++fb)
        Bf[fb] = __builtin_bit_cast(short8, fragbuf[fb * 64 + lane]);

    // A-side: wave's 16 rows; lane m = lane&15, k-offset q*8
    const int row = blockIdx.x * 64 + wv * 16 + (lane & 15);
    const float* frow = f + (size_t)row * HH + (lane >> 4) * 8;

    floatx4 acc0 = {0.f, 0.f, 0.f, 0.f};
    floatx4 acc1 = {0.f, 0.f, 0.f, 0.f};
    floatx4 acc2 = {0.f, 0.f, 0.f, 0.f};
#pragma unroll
    for (int kt = 0; kt < 8; ++kt) {
        const float4 v0 = *(const float4*)(frow + kt * 32);
        const float4 v1 = *(const float4*)(frow + kt * 32 + 4);
        const unsigned int a0 = bf16_rne(v0.x) | ((unsigned int)bf16_rne(v0.y) << 16);
        const unsigned int a1 = bf16_rne(v0.z) | ((unsigned int)bf16_rne(v0.w) << 16);
        const unsigned int a2 = bf16_rne(v1.x) | ((unsigned int)bf16_rne(v1.y) << 16);
        const unsigned int a3 = bf16_rne(v1.z) | ((unsigned int)bf16_rne(v1.w) << 16);
        const short8 Af = __builtin_bit_cast(short8, make_uint4(a0, a1, a2, a3));
        acc0 = __builtin_amdgcn_mfma_f32_16x16x32_bf16(Af, Bf[kt * 3 + 0], acc0, 0, 0, 0);
        acc1 = __builtin_amdgcn_mfma_f32_16x16x32_bf16(Af, Bf[kt * 3 + 1], acc1, 0, 0, 0);
        acc2 = __builtin_amdgcn_mfma_f32_16x16x32_bf16(Af, Bf[kt * 3 + 2], acc2, 0, 0, 0);
    }

    // epilogue: C/D layout col=lane&15, row=(lane>>4)*4+r
    const int outrow0 = blockIdx.x * 64 + wv * 16 + (lane >> 4) * 4;
    const int n = lane & 15;
#pragma unroll
    for (int r = 0; r < 4; ++r) {
        const size_t base = (size_t)(outrow0 + r) * TT;
        exem[base +  0 + n] = __expf(acc0[r] + biaslds[ 0 + n]);
        exem[base + 16 + n] = __expf(acc1[r] + biaslds[16 + n]);
        exem[base + 32 + n] = __expf(acc2[r] + biaslds[32 + n]);
    }
}

// ---------------------------------------------------------------------------
// Kernel 2: forward scan, scaled linear space, one wave per batch.
//   Entire exem[b] stream resident in LDS as bf16 -> zero global ops in loop.
// ---------------------------------------------------------------------------
__global__ __launch_bounds__(64) void crf_scan_kernel(
    const float* __restrict__ exem,    // [B*S, T]
    const float* __restrict__ trans,   // [T, T]
    const int*   __restrict__ lengths, // [B]
    const int*   __restrict__ tags,    // [B, S]
    float* __restrict__ out)           // [B]
{
    __shared__ __align__(16) unsigned short exb[SS * TT];  // 48 KiB bf16
    __shared__ __align__(16) float tlds[TT * TT];          // 9 KiB
    __shared__ __align__(16) float q[64];

    const int j = threadIdx.x;
    const int b = blockIdx.x;

    // preload emission stream (coalesced), cvt fp32 -> bf16 RNE
    const float4* src = (const float4*)(exem + (size_t)b * SS * TT);
    uint2* dst = (uint2*)exb;
    for (int i = j; i < SS * TT / 4; i += 64) {
        const float4 v = src[i];
        const unsigned int lo = bf16_rne(v.x) | ((unsigned int)bf16_rne(v.y) << 16);
        const unsigned int hi = bf16_rne(v.z) | ((unsigned int)bf16_rne(v.w) << 16);
        dst[i] = make_uint2(lo, hi);
    }
    for (int idx = j; idx < TT * TT; idx += 64) tlds[idx] = trans[idx];
    __syncthreads();

    const int len = lengths[b];

    // ---- gold path score ----
    float g = 0.0f;
    for (int s = j; s < len; s += 64) {
        const int tag  = tags[b * SS + s];
        const int from = (s == 0) ? START_IDX : tags[b * SS + s - 1];
        g += __logf(bf16_to_f32(exb[s * TT + tag])) + tlds[from * TT + tag];
    }
    g += __shfl_xor(g, 32); g += __shfl_xor(g, 16); g += __shfl_xor(g, 8);
    g += __shfl_xor(g, 4);  g += __shfl_xor(g, 2);  g += __shfl_xor(g, 1);

    // ---- E columns in registers ----
    const int jj = (j < TT) ? j : (TT - 1);
    float E[TT];
#pragma unroll
    for (int i = 0; i < TT; ++i)
        E[i] = (j < TT) ? __expf(tlds[i * TT + jj]) : 0.0f;
    const float Estop = (j < TT) ? __expf(tlds[j * TT + STOP_IDX]) : 0.0f;

    q[j] = (j == START_IDX) ? 1.0f : 0.0f;
    __builtin_amdgcn_wave_barrier();

    float L = 0.0f, qn = 0.0f;
    const int npair = len >> 1;

    for (int p = 0; p < npair; ++p) {
        const int t = p * 2;
        const float eA = bf16_to_f32(exb[t * TT + jj]);        // off-chain LDS
        const float eB = bf16_to_f32(exb[(t + 1) * TT + jj]);

        // ---- step A ----
        const float4* p4 = (const float4*)q;
        float pa[12];
#pragma unroll
        for (int i4 = 0; i4 < 12; ++i4) {
            const float4 pv = p4[i4];
            float u = pv.x * E[4*i4+0];
            u = fmaf(pv.y, E[4*i4+1], u);
            u = fmaf(pv.z, E[4*i4+2], u);
            u = fmaf(pv.w, E[4*i4+3], u);
            pa[i4] = u;
        }
        const float sA = (((pa[0]+pa[1]) + (pa[2]+pa[3]))
                        + ((pa[4]+pa[5]) + (pa[6]+pa[7])))
                        + ((pa[8]+pa[9]) + (pa[10]+pa[11]));
        q[j] = sA * eA;

        const float dd   = rfl(sA);
        const float facB = eB * __builtin_amdgcn_rcpf(dd);

        // ---- step B ----
        float pb[12];
#pragma unroll
        for (int i4 = 0; i4 < 12; ++i4) {
            const float4 pv = p4[i4];
            float u = pv.x * E[4*i4+0];
            u = fmaf(pv.y, E[4*i4+1], u);
            u = fmaf(pv.z, E[4*i4+2], u);
            u = fmaf(pv.w, E[4*i4+3], u);
            pb[i4] = u;
        }
        const float sB = (((pb[0]+pb[1]) + (pb[2]+pb[3]))
                        + ((pb[4]+pb[5]) + (pb[6]+pb[7])))
                        + ((pb[8]+pb[9]) + (pb[10]+pb[11]));
        qn = sB * facB;
        q[j] = qn;

        L += __logf(dd);
    }

    if (len & 1) {   // tail step, unnormalized (terminal log absorbs scale)
        const float eT = bf16_to_f32(exb[(len - 1) * TT + jj]);
        const float4* p4 = (const float4*)q;
        float pt[12];
#pragma unroll
        for (int i4 = 0; i4 < 12; ++i4) {
            const float4 pv = p4[i4];
            float u = pv.x * E[4*i4+0];
            u = fmaf(pv.y, E[4*i4+1], u);
            u = fmaf(pv.z, E[4*i4+2], u);
            u = fmaf(pv.w, E[4*i4+3], u);
            pt[i4] = u;
        }
        const float sT = (((pt[0]+pt[1]) + (pt[2]+pt[3]))
                        + ((pt[4]+pt[5]) + (pt[6]+pt[7])))
                        + ((pt[8]+pt[9]) + (pt[10]+pt[11]));
        qn = sT * eT;
        q[j] = qn;
    }

    // ---- terminal logsumexp ----
    float v = qn * Estop;
    v += __shfl_xor(v, 32); v += __shfl_xor(v, 16); v += __shfl_xor(v, 8);
    v += __shfl_xor(v, 4);  v += __shfl_xor(v, 2);  v += __shfl_xor(v, 1);
    const float all_paths = L + __logf(v);

    if (j == 0) {
        const int last = tags[b * SS + len - 1];
        out[b] = all_paths - (g + tlds[last * TT + STOP_IDX]);
    }
}

// ---------------------------------------------------------------------------
extern "C" void kernel_launch(void* const* d_in, const int* in_sizes, int n_in,
                              void* d_out, int out_size, void* d_ws, size_t ws_size,
                              hipStream_t stream) {
    const float* f       = (const float*)d_in[0];
    const float* w       = (const float*)d_in[1];
    const float* bias    = (const float*)d_in[2];
    const float* trans   = (const float*)d_in[3];
    const int*   lengths = (const int*)d_in[4];
    const int*   tags    = (const int*)d_in[5];
    float*       out     = (float*)d_out;

    float* exem = (float*)d_ws;   // [B*S, T] scratch, 3.1 MB

    emission_kernel<<<(BB * SS) / 64, 256, 0, stream>>>(f, w, bias, exem);
    crf_scan_kernel<<<BB, 64, 0, stream>>>(exem, trans, lengths, tags, out);
}

// Round 5
// 121.432 us; speedup vs baseline: 3.2086x; 1.5558x over previous
//
#include <hip/hip_runtime.h>
#include <math.h>

#define BB 32
#define SS 512
#define HH 256
#define TT 48
#define START_IDX 46
#define STOP_IDX 47

typedef __attribute__((ext_vector_type(8))) short short8;
typedef __attribute__((ext_vector_type(4))) float floatx4;

__device__ __forceinline__ float rfl(float x) {
    return __int_as_float(__builtin_amdgcn_readfirstlane(__float_as_int(x)));
}
__device__ __forceinline__ unsigned short bf16_rne(float x) {
    const unsigned int u = __float_as_uint(x);
    return (unsigned short)((u + 0x7fffu + ((u >> 16) & 1u)) >> 16);
}
__device__ __forceinline__ float bf2f(unsigned short h) {
    return __uint_as_float(((unsigned int)h) << 16);
}

// ---------------------------------------------------------------------------
// Kernel 1: exem[r][t] = exp(f.w + b) via bf16 MFMA -> bf16 output.
// ---------------------------------------------------------------------------
__global__ __launch_bounds__(256) void emission_kernel(
    const float* __restrict__ f, const float* __restrict__ w,
    const float* __restrict__ bias, unsigned short* __restrict__ exem)
{
    __shared__ __align__(16) unsigned short wb[HH * 50];
    __shared__ __align__(16) uint4 fragbuf[24 * 64];
    __shared__ float biaslds[TT];

    const int tid = threadIdx.x;
    for (int idx = tid; idx < HH * TT; idx += 256) {
        const int r = idx / TT;
        const int c = idx - r * TT;
        wb[r * 50 + c] = bf16_rne(w[idx]);
    }
    if (tid < TT) biaslds[tid] = bias[tid];
    __syncthreads();

    for (int idx = tid; idx < 24 * 64; idx += 256) {
        const int fb = idx >> 6;
        const int l  = idx & 63;
        const int kt = fb / 3;
        const int nt = fb - kt * 3;
        const int kbase = kt * 32 + (l >> 4) * 8;
        const int col   = nt * 16 + (l & 15);
        unsigned int p[4];
#pragma unroll
        for (int h = 0; h < 4; ++h) {
            const unsigned int lo = wb[(kbase + 2 * h)     * 50 + col];
            const unsigned int hi = wb[(kbase + 2 * h + 1) * 50 + col];
            p[h] = lo | (hi << 16);
        }
        fragbuf[idx] = make_uint4(p[0], p[1], p[2], p[3]);
    }
    __syncthreads();

    const int lane = tid & 63;
    const int wv   = tid >> 6;

    short8 Bf[24];
#pragma unroll
    for (int fb = 0; fb < 24; ++fb)
        Bf[fb] = __builtin_bit_cast(short8, fragbuf[fb * 64 + lane]);

    const int row = blockIdx.x * 64 + wv * 16 + (lane & 15);
    const float* frow = f + (size_t)row * HH + (lane >> 4) * 8;

    floatx4 acc0 = {0.f, 0.f, 0.f, 0.f};
    floatx4 acc1 = {0.f, 0.f, 0.f, 0.f};
    floatx4 acc2 = {0.f, 0.f, 0.f, 0.f};
#pragma unroll
    for (int kt = 0; kt < 8; ++kt) {
        const float4 v0 = *(const float4*)(frow + kt * 32);
        const float4 v1 = *(const float4*)(frow + kt * 32 + 4);
        const unsigned int a0 = bf16_rne(v0.x) | ((unsigned int)bf16_rne(v0.y) << 16);
        const unsigned int a1 = bf16_rne(v0.z) | ((unsigned int)bf16_rne(v0.w) << 16);
        const unsigned int a2 = bf16_rne(v1.x) | ((unsigned int)bf16_rne(v1.y) << 16);
        const unsigned int a3 = bf16_rne(v1.z) | ((unsigned int)bf16_rne(v1.w) << 16);
        const short8 Af = __builtin_bit_cast(short8, make_uint4(a0, a1, a2, a3));
        acc0 = __builtin_amdgcn_mfma_f32_16x16x32_bf16(Af, Bf[kt * 3 + 0], acc0, 0, 0, 0);
        acc1 = __builtin_amdgcn_mfma_f32_16x16x32_bf16(Af, Bf[kt * 3 + 1], acc1, 0, 0, 0);
        acc2 = __builtin_amdgcn_mfma_f32_16x16x32_bf16(Af, Bf[kt * 3 + 2], acc2, 0, 0, 0);
    }

    const int outrow0 = blockIdx.x * 64 + wv * 16 + (lane >> 4) * 4;
    const int n = lane & 15;
#pragma unroll
    for (int r = 0; r < 4; ++r) {
        unsigned short* e = exem + (size_t)(outrow0 + r) * TT;
        e[ 0 + n] = bf16_rne(__expf(acc0[r] + biaslds[ 0 + n]));
        e[16 + n] = bf16_rne(__expf(acc1[r] + biaslds[16 + n]));
        e[32 + n] = bf16_rne(__expf(acc2[r] + biaslds[32 + n]));
    }
}

// ---------------------------------------------------------------------------
// Kernel 2: per-(batch,chunk) product Q_c = PROD_{t in chunk} (D_t * E),
//   D_t = diag(exp(em_t)), chunks of 16 over t in [0, len-1).
//   One wave/block; acc in fp32 C-layout; per-iter: col-scale by e_t/sigma,
//   LDS transpose -> bf16 A-frags, 18 MFMA vs static E B-frags.
//   Output: Q^T col-major bf16 (stride 64) + logscale.
// ---------------------------------------------------------------------------
__global__ __launch_bounds__(64) void chunk_kernel(
    const unsigned short* __restrict__ exem,   // [B*S, T] bf16
    const float* __restrict__ trans,           // [T, T]
    const int*   __restrict__ lengths,         // [B]
    unsigned short* __restrict__ Qs,           // [B*32][48][64] bf16 (Q^T)
    float* __restrict__ Ls)                    // [B*32] logscale
{
    __shared__ __align__(16) unsigned short abuf[49 * 56];   // transpose scratch
    __shared__ __align__(16) unsigned short ebuf[16 * TT];   // emission rows

    const int bc = blockIdx.x;
    const int b = bc >> 5, c = bc & 31;
    const int len = lengths[b];
    int nsteps = (len - 1) - (c << 4);
    if (nsteps <= 0) return;
    if (nsteps > 16) nsteps = 16;

    const int j = threadIdx.x, g = j >> 4, cl = j & 15;

    // stage 16 emission rows (contiguous 1536 B)
    {
        const unsigned int* src = (const unsigned int*)(exem + ((size_t)b * SS + (c << 4)) * TT);
        unsigned int* dst = (unsigned int*)ebuf;
#pragma unroll
        for (int i = 0; i < 6; ++i) dst[j + i * 64] = src[j + i * 64];
    }

    // static E as B-frags (pairs consecutive-k, zero-pad k>=48)
    uint4 Bf[2][3];
#pragma unroll
    for (int kc = 0; kc < 2; ++kc)
#pragma unroll
        for (int nt = 0; nt < 3; ++nt) {
            unsigned int p[4];
#pragma unroll
            for (int h = 0; h < 4; ++h) {
                const int k = kc * 32 + g * 8 + 2 * h;
                const int n = nt * 16 + cl;
                const float lo = (k     < TT) ? __expf(trans[k * TT + n])       : 0.f;
                const float hi = (k + 1 < TT) ? __expf(trans[(k + 1) * TT + n]) : 0.f;
                p[h] = (unsigned int)bf16_rne(lo) | ((unsigned int)bf16_rne(hi) << 16);
            }
            Bf[kc][nt] = make_uint4(p[0], p[1], p[2], p[3]);
        }

    // acc = identity (C-layout: row = mt*16+4g+r, col = nt*16+cl)
    floatx4 acc[3][3];
#pragma unroll
    for (int mt = 0; mt < 3; ++mt)
#pragma unroll
        for (int nt = 0; nt < 3; ++nt)
#pragma unroll
            for (int r = 0; r < 4; ++r)
                acc[mt][nt][r] = (mt == nt && (4 * g + r) == cl) ? 1.f : 0.f;

    float sigprev = 1.f, L = 0.f;
    float ev[3];
#pragma unroll
    for (int nt = 0; nt < 3; ++nt) ev[nt] = bf2f(ebuf[nt * 16 + cl]);

    for (int s = 0; s < nsteps; ++s) {
        float invsig = 1.f;
        if (s) { L += __logf(sigprev); invsig = __builtin_amdgcn_rcpf(sigprev); }
        float fs[3];
#pragma unroll
        for (int nt = 0; nt < 3; ++nt) fs[nt] = ev[nt] * invsig;

        // col-scale + write bf16 transpose scratch (row-major [48][56])
#pragma unroll
        for (int mt = 0; mt < 3; ++mt)
#pragma unroll
            for (int nt = 0; nt < 3; ++nt)
#pragma unroll
                for (int r = 0; r < 4; ++r)
                    abuf[(mt * 16 + 4 * g + r) * 56 + nt * 16 + cl] =
                        bf16_rne(acc[mt][nt][r] * fs[nt]);

        // prefetch next emission row (off-chain)
        if (s + 1 < nsteps) {
#pragma unroll
            for (int nt = 0; nt < 3; ++nt)
                ev[nt] = bf2f(ebuf[(s + 1) * TT + nt * 16 + cl]);
        }

        // A-frags: lane holds row (mt*16+cl), k = kc*32 + g*8 .. +7
        uint4 Af[3][2];
#pragma unroll
        for (int mt = 0; mt < 3; ++mt) {
            Af[mt][0] = *(const uint4*)&abuf[(mt * 16 + cl) * 56 + g * 8];
            uint4 a1  = *(const uint4*)&abuf[(mt * 16 + cl) * 56 + 32 + g * 8];
            if (g >= 2) a1 = make_uint4(0, 0, 0, 0);   // k >= 48 pad
            Af[mt][1] = a1;
        }

        const floatx4 z = {0.f, 0.f, 0.f, 0.f};
#pragma unroll
        for (int mt = 0; mt < 3; ++mt)
#pragma unroll
            for (int nt = 0; nt < 3; ++nt) {
                floatx4 d = __builtin_amdgcn_mfma_f32_16x16x32_bf16(
                    __builtin_bit_cast(short8, Af[mt][0]),
                    __builtin_bit_cast(short8, Bf[0][nt]), z, 0, 0, 0);
                d = __builtin_amdgcn_mfma_f32_16x16x32_bf16(
                    __builtin_bit_cast(short8, Af[mt][1]),
                    __builtin_bit_cast(short8, Bf[1][nt]), d, 0, 0, 0);
                acc[mt][nt] = d;
            }
        sigprev = rfl(acc[0][0][0]);   // Q00 > 0 always
    }

    // store Q^T col-major (col stride 64): lane's 4 values are k-contiguous
    unsigned short* qb = Qs + (size_t)bc * (TT * 64);
#pragma unroll
    for (int mt = 0; mt < 3; ++mt)
#pragma unroll
        for (int nt = 0; nt < 3; ++nt) {
            const int col = nt * 16 + cl, row0 = mt * 16 + 4 * g;
            const unsigned int lo = (unsigned int)bf16_rne(acc[mt][nt][0])
                                  | ((unsigned int)bf16_rne(acc[mt][nt][1]) << 16);
            const unsigned int hi = (unsigned int)bf16_rne(acc[mt][nt][2])
                                  | ((unsigned int)bf16_rne(acc[mt][nt][3]) << 16);
            *(uint2*)&qb[col * 64 + row0] = make_uint2(lo, hi);
        }
    if (j == 0) Ls[bc] = L;
}

// ---------------------------------------------------------------------------
// Kernel 3: per-batch combine (32 serial matvecs via MFMA) + gold + output.
// ---------------------------------------------------------------------------
__global__ __launch_bounds__(64) void finalize_kernel(
    const unsigned short* __restrict__ exem,
    const float* __restrict__ trans,
    const int*   __restrict__ lengths,
    const int*   __restrict__ tags,
    const unsigned short* __restrict__ Qs,
    const float* __restrict__ Ls,
    float* __restrict__ out)
{
    __shared__ float tlds[TT * TT];
    __shared__ __align__(16) unsigned short vlds[64];

    const int j = threadIdx.x, b = blockIdx.x, g = j >> 4, cl = j & 15;

    for (int idx = j; idx < TT * TT; idx += 64) tlds[idx] = trans[idx];
    __builtin_amdgcn_wave_barrier();

    const int len = lengths[b];

    // gold path score
    float gold = 0.f;
    for (int s = j; s < len; s += 64) {
        const int tag  = tags[b * SS + s];
        const int from = (s == 0) ? START_IDX : tags[b * SS + s - 1];
        gold += __logf(bf2f(exem[((size_t)b * SS + s) * TT + tag])) + tlds[from * TT + tag];
    }
    gold += __shfl_xor(gold, 32); gold += __shfl_xor(gold, 16); gold += __shfl_xor(gold, 8);
    gold += __shfl_xor(gold, 4);  gold += __shfl_xor(gold, 2);  gold += __shfl_xor(gold, 1);

    // v = E[START, :]
    const float vj = (j < TT) ? __expf(tlds[START_IDX * TT + j]) : 0.f;
    vlds[j] = bf16_rne(vj);   // lanes >= 48 write bf16(0) = 0 (k-pad)

    const int nc = (len - 1 + 15) >> 4;
    const unsigned short* qbase = Qs + (size_t)(b * 32) * (TT * 64);

    float L = 0.f, inv = 1.f;
    floatx4 accn[3];

    // prefetch chunk 0 B-frags
    uint4 pB0[3], pB1[3];
#pragma unroll
    for (int nt = 0; nt < 3; ++nt) {
        pB0[nt] = *(const uint4*)&qbase[(size_t)0 * TT * 64 + (nt * 16 + cl) * 64 + g * 8];
        pB1[nt] = *(const uint4*)&qbase[(size_t)0 * TT * 64 + (nt * 16 + cl) * 64 + 32 + g * 8];
    }

    for (int cc = 0; cc < nc; ++cc) {
        uint4 B0[3], B1[3];
#pragma unroll
        for (int nt = 0; nt < 3; ++nt) { B0[nt] = pB0[nt]; B1[nt] = pB1[nt]; }

        // prefetch next chunk (clamped)
        const int cn = (cc + 1 < nc) ? cc + 1 : cc;
#pragma unroll
        for (int nt = 0; nt < 3; ++nt) {
            pB0[nt] = *(const uint4*)&qbase[(size_t)cn * TT * 64 + (nt * 16 + cl) * 64 + g * 8];
            pB1[nt] = *(const uint4*)&qbase[(size_t)cn * TT * 64 + (nt * 16 + cl) * 64 + 32 + g * 8];
        }

#pragma unroll
        for (int nt = 0; nt < 3; ++nt)
            if (g >= 2) B1[nt] = make_uint4(0, 0, 0, 0);   // k >= 48 garbage

        const uint4 A0 = *(const uint4*)&vlds[g * 8];        // v broadcast rows
        const uint4 A1 = *(const uint4*)&vlds[32 + g * 8];   // [48..63] = 0

        const floatx4 z = {0.f, 0.f, 0.f, 0.f};
#pragma unroll
        for (int nt = 0; nt < 3; ++nt) {
            floatx4 d = __builtin_amdgcn_mfma_f32_16x16x32_bf16(
                __builtin_bit_cast(short8, A0), __builtin_bit_cast(short8, B0[nt]), z, 0, 0, 0);
            d = __builtin_amdgcn_mfma_f32_16x16x32_bf16(
                __builtin_bit_cast(short8, A1), __builtin_bit_cast(short8, B1[nt]), d, 0, 0, 0);
            accn[nt] = d;
        }

        const float sig = rfl(accn[0][0]);   // v.Q[:,0] > 0
        inv = __builtin_amdgcn_rcpf(sig);
        L += __logf(sig) + Ls[b * 32 + cc];

        if (j < 16) {   // row 0 of D lives in lanes 0..15, reg 0
#pragma unroll
            for (int nt = 0; nt < 3; ++nt)
                vlds[nt * 16 + j] = bf16_rne(accn[nt][0] * inv);
        }
    }

    // terminal: sum_j v[j] * exp(em[len-1][j]) * exp(trans[j][STOP])
    float term = 0.f;
    if (j < 16) {
        const size_t erow = ((size_t)b * SS + (len - 1)) * TT;
#pragma unroll
        for (int nt = 0; nt < 3; ++nt) {
            const int col = nt * 16 + j;
            term += accn[nt][0] * inv * bf2f(exem[erow + col])
                    * __expf(tlds[col * TT + STOP_IDX]);
        }
    }
    term += __shfl_xor(term, 32); term += __shfl_xor(term, 16); term += __shfl_xor(term, 8);
    term += __shfl_xor(term, 4);  term += __shfl_xor(term, 2);  term += __shfl_xor(term, 1);

    if (j == 0) {
        const float all_paths = __logf(term) + L;
        const int last = tags[b * SS + len - 1];
        out[b] = all_paths - (gold + tlds[last * TT + STOP_IDX]);
    }
}

// ---------------------------------------------------------------------------
extern "C" void kernel_launch(void* const* d_in, const int* in_sizes, int n_in,
                              void* d_out, int out_size, void* d_ws, size_t ws_size,
                              hipStream_t stream) {
    const float* f       = (const float*)d_in[0];
    const float* w       = (const float*)d_in[1];
    const float* bias    = (const float*)d_in[2];
    const float* trans   = (const float*)d_in[3];
    const int*   lengths = (const int*)d_in[4];
    const int*   tags    = (const int*)d_in[5];
    float*       out     = (float*)d_out;

    // ws layout: exem bf16 [B*S*T] | Qs bf16 [B*32*48*64] | Ls f32 [B*32]
    unsigned short* exem = (unsigned short*)d_ws;                    // 1.50 MB
    unsigned short* Qs   = exem + (size_t)BB * SS * TT;              // 6.00 MB
    float*          Lsc  = (float*)(Qs + (size_t)BB * 32 * TT * 64); // 4 KB

    emission_kernel<<<(BB * SS) / 64, 256, 0, stream>>>(f, w, bias, exem);
    chunk_kernel<<<BB * 32, 64, 0, stream>>>(exem, trans, lengths, Qs, Lsc);
    finalize_kernel<<<BB, 64, 0, stream>>>(exem, trans, lengths, tags, Qs, Lsc, out);
}

// Round 6
// 116.458 us; speedup vs baseline: 3.3457x; 1.0427x over previous
//
#include <hip/hip_runtime.h>
#include <math.h>

#define BB 32
#define SS 512
#define HH 256
#define TT 48
#define START_IDX 46
#define STOP_IDX 47

typedef __attribute__((ext_vector_type(8))) short short8;
typedef __attribute__((ext_vector_type(4))) float floatx4;

__device__ __forceinline__ float rfl(float x) {
    return __int_as_float(__builtin_amdgcn_readfirstlane(__float_as_int(x)));
}
__device__ __forceinline__ unsigned int bf16_rne(float x) {
    const unsigned int u = __float_as_uint(x);
    return (u + 0x7fffu + ((u >> 16) & 1u)) >> 16;
}
__device__ __forceinline__ float bf2f(unsigned short h) {
    return __uint_as_float(((unsigned int)h) << 16);
}

// ---------------------------------------------------------------------------
// Kernel 1: exem[r][t] = exp(f.w + b) via bf16 MFMA (bf16 out).
//   f staged through LDS with coalesced reads (overlays dead w/frag buffers).
//   Block 0 wave 0 additionally prebuilds E B-frags into ws for chunk kernel.
// ---------------------------------------------------------------------------
__global__ __launch_bounds__(256) void emission_kernel(
    const float* __restrict__ f, const float* __restrict__ w,
    const float* __restrict__ bias, const float* __restrict__ trans,
    unsigned short* __restrict__ exem, uint4* __restrict__ Ebuf)
{
    __shared__ __align__(16) char smem[50176];
    __shared__ float biaslds[TT];
    unsigned short* wb = (unsigned short*)smem;       // [256][50] bf16
    uint4* fragbuf = (uint4*)(smem + 25600);          // [24][64]
    float* fl = (float*)smem;                         // [64][132] (overlay)

    const int tid = threadIdx.x;

    // prebuild E = exp(trans) B-frags once (block 0, wave 0) -> ws
    if (blockIdx.x == 0 && tid < 64) {
        const int g = tid >> 4, cl = tid & 15;
#pragma unroll
        for (int kc = 0; kc < 2; ++kc)
#pragma unroll
            for (int nt = 0; nt < 3; ++nt) {
                unsigned int p[4];
#pragma unroll
                for (int h2 = 0; h2 < 4; ++h2) {
                    const int k = kc * 32 + g * 8 + 2 * h2;
                    const int n = nt * 16 + cl;
                    const float lo = (k     < TT) ? __expf(trans[k * TT + n])       : 0.f;
                    const float hi = (k + 1 < TT) ? __expf(trans[(k + 1) * TT + n]) : 0.f;
                    p[h2] = bf16_rne(lo) | (bf16_rne(hi) << 16);
                }
                Ebuf[(kc * 3 + nt) * 64 + tid] = make_uint4(p[0], p[1], p[2], p[3]);
            }
    }

    // stage w -> bf16 LDS
    for (int idx = tid; idx < HH * TT; idx += 256) {
        const int r = idx / TT;
        const int c = idx - r * TT;
        wb[r * 50 + c] = (unsigned short)bf16_rne(w[idx]);
    }
    if (tid < TT) biaslds[tid] = bias[tid];
    __syncthreads();

    // build w B-frags
    for (int idx = tid; idx < 24 * 64; idx += 256) {
        const int fb = idx >> 6;
        const int l  = idx & 63;
        const int kt = fb / 3;
        const int nt = fb - kt * 3;
        const int kbase = kt * 32 + (l >> 4) * 8;
        const int col   = nt * 16 + (l & 15);
        unsigned int p[4];
#pragma unroll
        for (int h2 = 0; h2 < 4; ++h2) {
            const unsigned int lo = wb[(kbase + 2 * h2)     * 50 + col];
            const unsigned int hi = wb[(kbase + 2 * h2 + 1) * 50 + col];
            p[h2] = lo | (hi << 16);
        }
        fragbuf[idx] = make_uint4(p[0], p[1], p[2], p[3]);
    }
    __syncthreads();

    const int lane = tid & 63, wv = tid >> 6, g = lane >> 4, cl = lane & 15;

    short8 Bf[24];
#pragma unroll
    for (int fb = 0; fb < 24; ++fb)
        Bf[fb] = __builtin_bit_cast(short8, fragbuf[fb * 64 + lane]);
    __syncthreads();   // frags in regs; smem free for f overlay

    const int row0 = blockIdx.x * 64;
    floatx4 acc0 = {0.f,0.f,0.f,0.f}, acc1 = {0.f,0.f,0.f,0.f}, acc2 = {0.f,0.f,0.f,0.f};

    const int lr = wv * 16 + cl;
#pragma unroll
    for (int h = 0; h < 2; ++h) {
        // coalesced stage of f k-half: 64 rows x 128 floats
#pragma unroll
        for (int it = 0; it < 8; ++it) {
            const int idx = tid + it * 256;     // 0..2047 float4s
            const int r = idx >> 5, k4 = idx & 31;
            const float4 v = ((const float4*)f)[(size_t)(row0 + r) * 64 + h * 32 + k4];
            *(float4*)&fl[r * 132 + k4 * 4] = v;
        }
        __syncthreads();
#pragma unroll
        for (int kt = 0; kt < 4; ++kt) {
            const float4 v0 = *(const float4*)&fl[lr * 132 + kt * 32 + g * 8];
            const float4 v1 = *(const float4*)&fl[lr * 132 + kt * 32 + g * 8 + 4];
            const unsigned int a0 = bf16_rne(v0.x) | (bf16_rne(v0.y) << 16);
            const unsigned int a1 = bf16_rne(v0.z) | (bf16_rne(v0.w) << 16);
            const unsigned int a2 = bf16_rne(v1.x) | (bf16_rne(v1.y) << 16);
            const unsigned int a3 = bf16_rne(v1.z) | (bf16_rne(v1.w) << 16);
            const short8 Af = __builtin_bit_cast(short8, make_uint4(a0, a1, a2, a3));
            const int kg = h * 4 + kt;
            acc0 = __builtin_amdgcn_mfma_f32_16x16x32_bf16(Af, Bf[kg * 3 + 0], acc0, 0, 0, 0);
            acc1 = __builtin_amdgcn_mfma_f32_16x16x32_bf16(Af, Bf[kg * 3 + 1], acc1, 0, 0, 0);
            acc2 = __builtin_amdgcn_mfma_f32_16x16x32_bf16(Af, Bf[kg * 3 + 2], acc2, 0, 0, 0);
        }
        __syncthreads();   // all reads done before next-half overwrite
    }

    // epilogue: C/D layout col=lane&15, row=(lane>>4)*4+r
    const int outrow0 = row0 + wv * 16 + g * 4;
    const int n = cl;
#pragma unroll
    for (int r = 0; r < 4; ++r) {
        unsigned short* e = exem + (size_t)(outrow0 + r) * TT;
        e[ 0 + n] = (unsigned short)bf16_rne(__expf(acc0[r] + biaslds[ 0 + n]));
        e[16 + n] = (unsigned short)bf16_rne(__expf(acc1[r] + biaslds[16 + n]));
        e[32 + n] = (unsigned short)bf16_rne(__expf(acc2[r] + biaslds[32 + n]));
    }
}

// ---------------------------------------------------------------------------
// Kernel 2: chunk products Q_c = PROD_{t in chunk}(D_t*E), 16 steps/chunk.
//   Rows evolve independently -> 3 waves/block, 16 rows each; private LDS
//   transpose scratch; per-rowblock normalization at step 8 (logged in Ls3).
// ---------------------------------------------------------------------------
__global__ __launch_bounds__(192) void chunk_kernel(
    const unsigned short* __restrict__ exem,   // [B*S, T] bf16
    const uint4* __restrict__ Ebuf,            // prebuilt E B-frags
    const int*   __restrict__ lengths,
    unsigned short* __restrict__ Qs,           // [B*32][48][64] bf16 (col-major Q)
    float* __restrict__ Ls3)                   // [B*32][3] per-rowblock logscale
{
    __shared__ __align__(8)  unsigned short ebuf[16 * TT];
    __shared__ __align__(16) unsigned short abuf[3][17 * 56];

    const int bc = blockIdx.x, b = bc >> 5, c = bc & 31;
    const int len = lengths[b];
    int nsteps = (len - 1) - (c << 4);
    if (nsteps <= 0) return;
    if (nsteps > 16) nsteps = 16;

    const int tid = threadIdx.x;
    const int rb = tid >> 6, l = tid & 63, g = l >> 4, cl = l & 15;

    // stage 16 emission rows (1536 B, coalesced)
    {
        const unsigned int* src = (const unsigned int*)(exem + ((size_t)b * SS + (c << 4)) * TT);
        unsigned int* dst = (unsigned int*)ebuf;
        dst[tid] = src[tid];
        dst[tid + 192] = src[tid + 192];
    }

    uint4 Bf[2][3];
#pragma unroll
    for (int kc = 0; kc < 2; ++kc)
#pragma unroll
        for (int nt = 0; nt < 3; ++nt)
            Bf[kc][nt] = Ebuf[(kc * 3 + nt) * 64 + l];

    __syncthreads();

    // acc = identity rows [16rb, 16rb+16)
    floatx4 acc[3];
#pragma unroll
    for (int nt = 0; nt < 3; ++nt)
#pragma unroll
        for (int r = 0; r < 4; ++r)
            acc[nt][r] = (16 * rb + 4 * g + r == nt * 16 + cl) ? 1.f : 0.f;

    float ev[3];
#pragma unroll
    for (int nt = 0; nt < 3; ++nt) ev[nt] = bf2f(ebuf[nt * 16 + cl]);

    float Lrb = 0.f;
    unsigned short* aw = abuf[rb];

    for (int s = 0; s < nsteps; ++s) {
        float scale = 1.f;
        if (s == 8) {   // sigma from post-step-7 acc; applied exactly once
            const float sig = rfl(acc[0][0]);
            Lrb = __logf(sig);
            scale = __builtin_amdgcn_rcpf(sig);
        }
        const float f0 = ev[0] * scale, f1 = ev[1] * scale, f2 = ev[2] * scale;
#pragma unroll
        for (int r = 0; r < 4; ++r) {
            const int rw = (4 * g + r) * 56;
            aw[rw +      cl] = (unsigned short)bf16_rne(acc[0][r] * f0);
            aw[rw + 16 + cl] = (unsigned short)bf16_rne(acc[1][r] * f1);
            aw[rw + 32 + cl] = (unsigned short)bf16_rne(acc[2][r] * f2);
        }
        if (s + 1 < nsteps) {   // off-chain emission prefetch
#pragma unroll
            for (int nt = 0; nt < 3; ++nt)
                ev[nt] = bf2f(ebuf[(s + 1) * TT + nt * 16 + cl]);
        }
        uint4 a0 = *(const uint4*)&aw[cl * 56 + g * 8];
        uint4 a1 = *(const uint4*)&aw[cl * 56 + 32 + g * 8];
        if (g >= 2) a1 = make_uint4(0, 0, 0, 0);   // k >= 48 pad
        const floatx4 z = {0.f, 0.f, 0.f, 0.f};
#pragma unroll
        for (int nt = 0; nt < 3; ++nt) {
            floatx4 d = __builtin_amdgcn_mfma_f32_16x16x32_bf16(
                __builtin_bit_cast(short8, a0), __builtin_bit_cast(short8, Bf[0][nt]), z, 0, 0, 0);
            d = __builtin_amdgcn_mfma_f32_16x16x32_bf16(
                __builtin_bit_cast(short8, a1), __builtin_bit_cast(short8, Bf[1][nt]), d, 0, 0, 0);
            acc[nt] = d;
        }
    }

    // store col-major Q (qb[col*64 + row]); lane's 4 rows contiguous
    unsigned short* qb = Qs + (size_t)bc * (TT * 64);
#pragma unroll
    for (int nt = 0; nt < 3; ++nt) {
        const unsigned int lo = bf16_rne(acc[nt][0]) | (bf16_rne(acc[nt][1]) << 16);
        const unsigned int hi = bf16_rne(acc[nt][2]) | (bf16_rne(acc[nt][3]) << 16);
        *(uint2*)&qb[(nt * 16 + cl) * 64 + 16 * rb + 4 * g] = make_uint2(lo, hi);
    }
    if (l == 0) Ls3[bc * 3 + rb] = Lrb;
}

// ---------------------------------------------------------------------------
// Kernel 3: per-batch combine (32 serial MFMA matvecs) + gold + output.
//   Per-rowblock chunk scales reconciled via exp factors at the v-write.
// ---------------------------------------------------------------------------
__global__ __launch_bounds__(64) void finalize_kernel(
    const unsigned short* __restrict__ exem,
    const float* __restrict__ trans,
    const int*   __restrict__ lengths,
    const int*   __restrict__ tags,
    const unsigned short* __restrict__ Qs,
    const float* __restrict__ Ls3,
    float* __restrict__ out)
{
    __shared__ float tlds[TT * TT];
    __shared__ __align__(16) unsigned short vlds[64];
    __shared__ float Lsl[96];

    const int j = threadIdx.x, b = blockIdx.x, g = j >> 4, cl = j & 15;

    for (int idx = j; idx < TT * TT; idx += 64) tlds[idx] = trans[idx];

    const int len = lengths[b];
    const int nc = (len - 1 + 15) >> 4;
    for (int i = j; i < nc * 3; i += 64) Lsl[i] = Ls3[b * 96 + i];
    __builtin_amdgcn_wave_barrier();

    // gold path score
    float gold = 0.f;
    for (int s = j; s < len; s += 64) {
        const int tag  = tags[b * SS + s];
        const int from = (s == 0) ? START_IDX : tags[b * SS + s - 1];
        gold += __logf(bf2f(exem[((size_t)b * SS + s) * TT + tag])) + tlds[from * TT + tag];
    }
    gold += __shfl_xor(gold, 32); gold += __shfl_xor(gold, 16); gold += __shfl_xor(gold, 8);
    gold += __shfl_xor(gold, 4);  gold += __shfl_xor(gold, 2);  gold += __shfl_xor(gold, 1);

    // v init: E[START,:] with chunk-0 rowblock factors folded in
    const float R0 = Lsl[0];
    float vj = 0.f;
    if (j < TT) vj = __expf(tlds[START_IDX * TT + j]) * __expf(Lsl[j >> 4] - R0);
    vlds[j] = (unsigned short)bf16_rne(vj);   // j>=48 -> 0 (k-pad)
    float L = R0;

    const unsigned short* qbase = Qs + (size_t)(b * 32) * (TT * 64);
    floatx4 accn[3];
    float inv = 1.f;

    uint4 pB0[3], pB1[3];
#pragma unroll
    for (int nt = 0; nt < 3; ++nt) {
        pB0[nt] = *(const uint4*)&qbase[(nt * 16 + cl) * 64 + g * 8];
        pB1[nt] = *(const uint4*)&qbase[(nt * 16 + cl) * 64 + 32 + g * 8];
    }

    for (int cc = 0; cc < nc; ++cc) {
        uint4 B0[3], B1[3];
#pragma unroll
        for (int nt = 0; nt < 3; ++nt) { B0[nt] = pB0[nt]; B1[nt] = pB1[nt]; }

        const int cn = (cc + 1 < nc) ? cc + 1 : cc;
#pragma unroll
        for (int nt = 0; nt < 3; ++nt) {
            pB0[nt] = *(const uint4*)&qbase[(size_t)cn * TT * 64 + (nt * 16 + cl) * 64 + g * 8];
            pB1[nt] = *(const uint4*)&qbase[(size_t)cn * TT * 64 + (nt * 16 + cl) * 64 + 32 + g * 8];
        }
#pragma unroll
        for (int nt = 0; nt < 3; ++nt)
            if (g >= 2) B1[nt] = make_uint4(0, 0, 0, 0);

        const uint4 A0 = *(const uint4*)&vlds[g * 8];
        const uint4 A1 = *(const uint4*)&vlds[32 + g * 8];

        const floatx4 z = {0.f, 0.f, 0.f, 0.f};
#pragma unroll
        for (int nt = 0; nt < 3; ++nt) {
            floatx4 d = __builtin_amdgcn_mfma_f32_16x16x32_bf16(
                __builtin_bit_cast(short8, A0), __builtin_bit_cast(short8, B0[nt]), z, 0, 0, 0);
            d = __builtin_amdgcn_mfma_f32_16x16x32_bf16(
                __builtin_bit_cast(short8, A1), __builtin_bit_cast(short8, B1[nt]), d, 0, 0, 0);
            accn[nt] = d;
        }

        const float sig = rfl(accn[0][0]);   // > 0 always
        inv = __builtin_amdgcn_rcpf(sig);

        if (cc + 1 < nc) {
            const float Rn = Lsl[(cc + 1) * 3];
            const float fa0 = __expf(Lsl[(cc + 1) * 3 + 0] - Rn);
            const float fa1 = __expf(Lsl[(cc + 1) * 3 + 1] - Rn);
            const float fa2 = __expf(Lsl[(cc + 1) * 3 + 2] - Rn);
            L += __logf(sig) + Rn;
            if (j < 16) {   // row 0 of result: lanes 0..15, reg 0
                vlds[ 0 + j] = (unsigned short)bf16_rne(accn[0][0] * inv * fa0);
                vlds[16 + j] = (unsigned short)bf16_rne(accn[1][0] * inv * fa1);
                vlds[32 + j] = (unsigned short)bf16_rne(accn[2][0] * inv * fa2);
            }
        } else {
            L += __logf(sig);
        }
    }

    // terminal: sum_n v[n] * exem[len-1][n] * exp(trans[n][STOP])
    float term = 0.f;
    if (j < 16) {
        const size_t erow = ((size_t)b * SS + (len - 1)) * TT;
#pragma unroll
        for (int nt = 0; nt < 3; ++nt) {
            const int col = nt * 16 + j;
            term += accn[nt][0] * inv * bf2f(exem[erow + col])
                    * __expf(tlds[col * TT + STOP_IDX]);
        }
    }
    term += __shfl_xor(term, 32); term += __shfl_xor(term, 16); term += __shfl_xor(term, 8);
    term += __shfl_xor(term, 4);  term += __shfl_xor(term, 2);  term += __shfl_xor(term, 1);

    if (j == 0) {
        const float all_paths = __logf(term) + L;
        const int last = tags[b * SS + len - 1];
        out[b] = all_paths - (gold + tlds[last * TT + STOP_IDX]);
    }
}

// ---------------------------------------------------------------------------
extern "C" void kernel_launch(void* const* d_in, const int* in_sizes, int n_in,
                              void* d_out, int out_size, void* d_ws, size_t ws_size,
                              hipStream_t stream) {
    const float* f       = (const float*)d_in[0];
    const float* w       = (const float*)d_in[1];
    const float* bias    = (const float*)d_in[2];
    const float* trans   = (const float*)d_in[3];
    const int*   lengths = (const int*)d_in[4];
    const int*   tags    = (const int*)d_in[5];
    float*       out     = (float*)d_out;

    // ws: exem bf16 [B*S*T] | Qs bf16 [B*32*48*64] | Ls3 f32 [B*32*3] | Ebuf
    char* ws = (char*)d_ws;
    unsigned short* exem = (unsigned short*)ws;                  // 1,572,864 B
    unsigned short* Qs   = (unsigned short*)(ws + 1572864);      // 6,291,456 B
    float*          Lsc  = (float*)(ws + 7864320);               // 12,288 B
    uint4*          Ebuf = (uint4*)(ws + 7876608);               // 6,144 B

    emission_kernel<<<(BB * SS) / 64, 256, 0, stream>>>(f, w, bias, trans, exem, Ebuf);
    chunk_kernel<<<BB * 32, 192, 0, stream>>>(exem, Ebuf, lengths, Qs, Lsc);
    finalize_kernel<<<BB, 64, 0, stream>>>(exem, trans, lengths, tags, Qs, Lsc, out);
}